// Round 5
// baseline (351.250 us; speedup 1.0000x reference)
//
#include <hip/hip_runtime.h>
#include <hip/hip_bf16.h>

#define EMBED 384
#define SEQ   1024
#define NBATCH 16
#define NH    6
#define HD    64

typedef __bf16 bf16;
typedef bf16  bf16x8 __attribute__((ext_vector_type(8)));
typedef bf16  bf16x4 __attribute__((ext_vector_type(4)));
typedef float f32x4  __attribute__((ext_vector_type(4)));

#define MFMA16(a, b, c) __builtin_amdgcn_mfma_f32_16x16x32_bf16((a), (b), (c), 0, 0, 0)

// ---------------------------------------------------------------------------
// K-1: f32 -> bf16 weight conversion (w_qkv, w_out)
// ---------------------------------------------------------------------------
__global__ __launch_bounds__(256) void k_cvt(const float* __restrict__ src,
                                             bf16* __restrict__ dst, int n) {
    int i = blockIdx.x * 256 + threadIdx.x;
    if (i < n) dst[i] = (bf16)src[i];
}

// ---------------------------------------------------------------------------
// K0: x[n][c][s] (f32) -> tok[n][s][c] (bf16)  tile transpose through LDS
// ---------------------------------------------------------------------------
__global__ __launch_bounds__(256) void k_transpose(const float* __restrict__ x,
                                                   bf16* __restrict__ tok) {
    __shared__ bf16 tile[64][66];
    int n  = blockIdx.z;
    int s0 = blockIdx.x * 64;
    int c0 = blockIdx.y * 64;
    int tid = threadIdx.x;

    int sl  = tid & 63;
    int cl0 = tid >> 6;  // 0..3
#pragma unroll
    for (int i = 0; i < 16; ++i) {
        int cl = cl0 + i * 4;
        tile[cl][sl] = (bf16)x[((size_t)n * EMBED + (c0 + cl)) * SEQ + s0 + sl];
    }
    __syncthreads();
    int cl  = tid & 63;
    int sl0 = tid >> 6;
#pragma unroll
    for (int i = 0; i < 16; ++i) {
        int s = sl0 + i * 4;
        tok[((size_t)n * SEQ + (s0 + s)) * EMBED + c0 + cl] = tile[cl][s];
    }
}

// ---------------------------------------------------------------------------
// K1: qkv[n][s][o] = sum_c tok[n][s][c] * wqkv[o][c]
//   scatter into q[n][h][s][d], k[n][h][s][d], vT[n][h][d][s]
// ---------------------------------------------------------------------------
__global__ __launch_bounds__(256) void k_qkv(const bf16* __restrict__ tok,
                                             const bf16* __restrict__ wqkv,
                                             bf16* __restrict__ qout,
                                             bf16* __restrict__ kout,
                                             bf16* __restrict__ vtout) {
    int n    = blockIdx.y;
    int bm   = blockIdx.x & 7;   // 8 s-tiles
    int bn   = blockIdx.x >> 3;  // 9 o-tiles
    int wave = threadIdx.x >> 6;
    int lane = threadIdx.x & 63;
    int row16 = lane & 15;
    int quad  = lane >> 4;
    int s_base = bm * 128 + (wave >> 1) * 64;
    int o_base = bn * 128 + (wave & 1) * 64;

    const bf16* A = tok + (size_t)n * SEQ * EMBED;

    f32x4 acc[4][4] = {};
    for (int kk = 0; kk < EMBED; kk += 32) {
        bf16x8 af[4], bfr[4];
#pragma unroll
        for (int mt = 0; mt < 4; ++mt)
            af[mt] = *reinterpret_cast<const bf16x8*>(
                A + (size_t)(s_base + mt * 16 + row16) * EMBED + kk + quad * 8);
#pragma unroll
        for (int nt = 0; nt < 4; ++nt)
            bfr[nt] = *reinterpret_cast<const bf16x8*>(
                wqkv + (size_t)(o_base + nt * 16 + row16) * EMBED + kk + quad * 8);
#pragma unroll
        for (int mt = 0; mt < 4; ++mt)
#pragma unroll
            for (int nt = 0; nt < 4; ++nt)
                acc[mt][nt] = MFMA16(af[mt], bfr[nt], acc[mt][nt]);
    }

    int part = (bn * 128) / EMBED;  // o-tile never crosses a part boundary
#pragma unroll
    for (int mt = 0; mt < 4; ++mt)
#pragma unroll
        for (int nt = 0; nt < 4; ++nt) {
            int o   = o_base + nt * 16 + row16;
            int rem = o - part * EMBED;
            int h = rem >> 6;
            int d = rem & 63;
            if (part < 2) {
                bf16* dst = (part == 0) ? qout : kout;
#pragma unroll
                for (int r = 0; r < 4; ++r) {
                    int s = s_base + mt * 16 + quad * 4 + r;
                    dst[(((size_t)n * NH + h) * SEQ + s) * HD + d] = (bf16)acc[mt][nt][r];
                }
            } else {
                int s = s_base + mt * 16 + quad * 4;  // 4 consecutive s -> 8B store
                bf16x4 pack;
#pragma unroll
                for (int r = 0; r < 4; ++r) pack[r] = (bf16)acc[mt][nt][r];
                *reinterpret_cast<bf16x4*>(
                    &vtout[(((size_t)n * NH + h) * HD + d) * SEQ + s]) = pack;
            }
        }
}

// ---------------------------------------------------------------------------
// K2: attention. S^T = K·Q^T so the C-layout gives each lane 4 contiguous
//   t-values of P[row=lane&15] -> ds_write_b64 / ds_read_b128 round trip.
//   K register-prefetched one iteration ahead; load issue order (V, then K
//   prefetch) chosen so PV's FIFO vmcnt wait leaves the prefetch in flight.
// ---------------------------------------------------------------------------
__global__ __launch_bounds__(256) void k_attn(const bf16* __restrict__ q,
                                              const bf16* __restrict__ kmat,
                                              const bf16* __restrict__ vT,
                                              bf16* __restrict__ ao) {
    __shared__ __align__(16) bf16 pshare[4][16][72];  // wave-private P tile
    int nh = blockIdx.y;  // 0..95
    int n = nh / NH, h = nh % NH;
    int qt   = blockIdx.x;  // 0..15
    int wave = threadIdx.x >> 6;
    int lane = threadIdx.x & 63;
    int row16 = lane & 15;
    int quad  = lane >> 4;
    int s_row = qt * 64 + wave * 16;

    const bf16* qh = q    + ((size_t)n * NH + h) * SEQ * HD;
    const bf16* kh = kmat + ((size_t)n * NH + h) * SEQ * HD;
    const bf16* vh = vT   + ((size_t)n * NH + h) * HD * SEQ;

    bf16x8 qf0 = *reinterpret_cast<const bf16x8*>(qh + (size_t)(s_row + row16) * HD + quad * 8);
    bf16x8 qf1 = *reinterpret_cast<const bf16x8*>(qh + (size_t)(s_row + row16) * HD + 32 + quad * 8);

    // K fragments for t-tile 0 (A-operand of S^T: rows are K rows)
    bf16x8 kc[4][2];
#pragma unroll
    for (int nt = 0; nt < 4; ++nt) {
        kc[nt][0] = *reinterpret_cast<const bf16x8*>(kh + (size_t)(nt * 16 + row16) * HD + quad * 8);
        kc[nt][1] = *reinterpret_cast<const bf16x8*>(kh + (size_t)(nt * 16 + row16) * HD + 32 + quad * 8);
    }

    float lsum[4] = {0.f, 0.f, 0.f, 0.f};
    f32x4 oacc[4] = {};
    const float kScale = 0.180336879f;  // log2(e)/8

#pragma unroll
    for (int t0 = 0; t0 < SEQ; t0 += 64) {
        // (1) V loads for THIS tile — issued first so PV's vmcnt wait
        //     does not drain the K prefetch behind them.
        bf16x8 vf[4][2];
#pragma unroll
        for (int dt = 0; dt < 4; ++dt) {
            vf[dt][0] = *reinterpret_cast<const bf16x8*>(
                vh + (size_t)(dt * 16 + row16) * SEQ + t0 + quad * 8);
            vf[dt][1] = *reinterpret_cast<const bf16x8*>(
                vh + (size_t)(dt * 16 + row16) * SEQ + t0 + 32 + quad * 8);
        }
        // (2) K prefetch for NEXT tile
        bf16x8 kn[4][2];
        if (t0 + 64 < SEQ) {
#pragma unroll
            for (int nt = 0; nt < 4; ++nt) {
                kn[nt][0] = *reinterpret_cast<const bf16x8*>(
                    kh + (size_t)(t0 + 64 + nt * 16 + row16) * HD + quad * 8);
                kn[nt][1] = *reinterpret_cast<const bf16x8*>(
                    kh + (size_t)(t0 + 64 + nt * 16 + row16) * HD + 32 + quad * 8);
            }
        }
        // (3) S^T = K·Q^T: D[t-row][q-col]; lane ends up holding
        //     P[m=lane&15][t=16nt+4quad+r] — contiguous t runs.
        f32x4 sacc[4] = {};
#pragma unroll
        for (int nt = 0; nt < 4; ++nt) {
            sacc[nt] = MFMA16(kc[nt][0], qf0, sacc[nt]);
            sacc[nt] = MFMA16(kc[nt][1], qf1, sacc[nt]);
        }
        // (4) P = exp(S/8), packed 8B LDS writes
#pragma unroll
        for (int nt = 0; nt < 4; ++nt) {
            bf16x4 pk;
            float ps = 0.f;
#pragma unroll
            for (int r = 0; r < 4; ++r) {
                float e = __builtin_amdgcn_exp2f(sacc[nt][r] * kScale);
                ps += e;
                pk[r] = (bf16)e;
            }
            lsum[nt] += ps;
            *reinterpret_cast<bf16x4*>(&pshare[wave][row16][nt * 16 + quad * 4]) = pk;
        }
        __builtin_amdgcn_wave_barrier();  // order LDS write -> read (wave-private)
        bf16x8 pf0 = *reinterpret_cast<const bf16x8*>(&pshare[wave][row16][quad * 8]);
        bf16x8 pf1 = *reinterpret_cast<const bf16x8*>(&pshare[wave][row16][32 + quad * 8]);
        __builtin_amdgcn_wave_barrier();  // order read -> next iter's writes
        // (5) O += P·V
#pragma unroll
        for (int dt = 0; dt < 4; ++dt) {
            oacc[dt] = MFMA16(pf0, vf[dt][0], oacc[dt]);
            oacc[dt] = MFMA16(pf1, vf[dt][1], oacc[dt]);
        }
#pragma unroll
        for (int nt = 0; nt < 4; ++nt) {
            kc[nt][0] = kn[nt][0];
            kc[nt][1] = kn[nt][1];
        }
    }

    // row sums: lane holds partials for row m=lane&15 over t ≡ {4q..4q+3} mod 16
    float tot = (lsum[0] + lsum[1]) + (lsum[2] + lsum[3]);
    tot += __shfl_xor(tot, 16, 64);
    tot += __shfl_xor(tot, 32, 64);
    float inv = 1.0f / tot;  // valid at every lane for row = lane&15

    // redistribute: output row j = quad*4+r needs inv held at lane j
    float linv[4];
#pragma unroll
    for (int r = 0; r < 4; ++r) linv[r] = __shfl(inv, quad * 4 + r, 64);

#pragma unroll
    for (int dt = 0; dt < 4; ++dt)
#pragma unroll
        for (int r = 0; r < 4; ++r) {
            int s = s_row + quad * 4 + r;
            int d = dt * 16 + row16;
            ao[((size_t)n * SEQ + s) * EMBED + h * HD + d] = (bf16)(oacc[dt][r] * linv[r]);
        }
}

// ---------------------------------------------------------------------------
// K3: out[n][o][s] = bias[o] + sum_c ao[n][s][c] * wout[o][c]   (f32 output)
// ---------------------------------------------------------------------------
__global__ __launch_bounds__(256) void k_proj(const bf16* __restrict__ ao,
                                              const bf16* __restrict__ wout,
                                              const float* __restrict__ bout,
                                              float* __restrict__ out) {
    int n    = blockIdx.y;
    int bm   = blockIdx.x & 7;   // 8 s-tiles
    int bn   = blockIdx.x >> 3;  // 3 o-tiles
    int wave = threadIdx.x >> 6;
    int lane = threadIdx.x & 63;
    int row16 = lane & 15;
    int quad  = lane >> 4;
    int s_base = bm * 128 + (wave >> 1) * 64;
    int o_base = bn * 128 + (wave & 1) * 64;

    const bf16* A = ao + (size_t)n * SEQ * EMBED;

    f32x4 acc[4][4] = {};
    for (int kk = 0; kk < EMBED; kk += 32) {
        bf16x8 af[4], bfr[4];
#pragma unroll
        for (int mt = 0; mt < 4; ++mt)
            af[mt] = *reinterpret_cast<const bf16x8*>(
                A + (size_t)(s_base + mt * 16 + row16) * EMBED + kk + quad * 8);
#pragma unroll
        for (int nt = 0; nt < 4; ++nt)
            bfr[nt] = *reinterpret_cast<const bf16x8*>(
                wout + (size_t)(o_base + nt * 16 + row16) * EMBED + kk + quad * 8);
#pragma unroll
        for (int mt = 0; mt < 4; ++mt)
#pragma unroll
            for (int nt = 0; nt < 4; ++nt)
                acc[mt][nt] = MFMA16(af[mt], bfr[nt], acc[mt][nt]);
    }

#pragma unroll
    for (int nt = 0; nt < 4; ++nt) {
        int o = o_base + nt * 16 + row16;
        float bias = bout[o];
#pragma unroll
        for (int mt = 0; mt < 4; ++mt) {
            int s = s_base + mt * 16 + quad * 4;  // 4 consecutive s, 16B store
            f32x4 pack;
#pragma unroll
            for (int r = 0; r < 4; ++r) pack[r] = acc[mt][nt][r] + bias;
            *reinterpret_cast<f32x4*>(out + ((size_t)n * EMBED + o) * SEQ + s) = pack;
        }
    }
}

// ---------------------------------------------------------------------------
extern "C" void kernel_launch(void* const* d_in, const int* in_sizes, int n_in,
                              void* d_out, int out_size, void* d_ws, size_t ws_size,
                              hipStream_t stream) {
    const float *x = nullptr, *wqkv = nullptr, *wout = nullptr, *bout = nullptr;
    for (int i = 0; i < n_in; ++i) {
        switch (in_sizes[i]) {
            case NBATCH * EMBED * SEQ:   x    = (const float*)d_in[i]; break;  // 6291456
            case 3 * EMBED * EMBED:      wqkv = (const float*)d_in[i]; break;  // 442368
            case EMBED * EMBED:          wout = (const float*)d_in[i]; break;  // 147456
            case EMBED:                  bout = (const float*)d_in[i]; break;  // 384
        }
    }
    float* out = (float*)d_out;

    bf16* ws = (bf16*)d_ws;
    const size_t NE = (size_t)NBATCH * SEQ * EMBED;  // 6.29M elems
    bf16* tok   = ws;
    bf16* q     = ws + NE;
    bf16* k     = ws + 2 * NE;
    bf16* vT    = ws + 3 * NE;
    bf16* ao    = ws + 4 * NE;
    bf16* wqkvb = ws + 5 * NE;
    bf16* woutb = wqkvb + 3 * EMBED * EMBED;

    const int nqkv = 3 * EMBED * EMBED;
    const int nout = EMBED * EMBED;
    k_cvt<<<dim3((nqkv + 255) / 256), 256, 0, stream>>>(wqkv, wqkvb, nqkv);
    k_cvt<<<dim3((nout + 255) / 256), 256, 0, stream>>>(wout, woutb, nout);

    k_transpose<<<dim3(16, 6, 16), 256, 0, stream>>>(x, tok);
    k_qkv<<<dim3(72, 16), 256, 0, stream>>>(tok, wqkvb, q, k, vT);
    k_attn<<<dim3(16, 96), 256, 0, stream>>>(q, k, vT, ao);
    k_proj<<<dim3(24, 16), 256, 0, stream>>>(ao, woutb, bout, out);
}

// Round 6
// 239.956 us; speedup vs baseline: 1.4638x; 1.4638x over previous
//
#include <hip/hip_runtime.h>
#include <hip/hip_bf16.h>

#define EMBED 384
#define SEQ   1024
#define NBATCH 16
#define NH    6
#define HD    64

typedef __bf16 bf16;
typedef bf16  bf16x8 __attribute__((ext_vector_type(8)));
typedef bf16  bf16x4 __attribute__((ext_vector_type(4)));
typedef float f32x4  __attribute__((ext_vector_type(4)));

#define MFMA16(a, b, c) __builtin_amdgcn_mfma_f32_16x16x32_bf16((a), (b), (c), 0, 0, 0)

// async global->LDS, 16B per lane; LDS dst = wave-uniform base + lane*16
__device__ __forceinline__ void gload_lds16(const void* g, void* l) {
    __builtin_amdgcn_global_load_lds(
        (const __attribute__((address_space(1))) void*)g,
        (__attribute__((address_space(3))) void*)l, 16, 0, 0);
}

// ---------------------------------------------------------------------------
// K-1: f32 -> bf16 weight conversion (w_qkv, w_out)
// ---------------------------------------------------------------------------
__global__ __launch_bounds__(256) void k_cvt(const float* __restrict__ src,
                                             bf16* __restrict__ dst, int n) {
    int i = blockIdx.x * 256 + threadIdx.x;
    if (i < n) dst[i] = (bf16)src[i];
}

// ---------------------------------------------------------------------------
// K0: x[n][c][s] (f32) -> tok[n][s][c] (bf16)  tile transpose through LDS
// ---------------------------------------------------------------------------
__global__ __launch_bounds__(256) void k_transpose(const float* __restrict__ x,
                                                   bf16* __restrict__ tok) {
    __shared__ bf16 tile[64][66];
    int n  = blockIdx.z;
    int s0 = blockIdx.x * 64;
    int c0 = blockIdx.y * 64;
    int tid = threadIdx.x;

    int sl  = tid & 63;
    int cl0 = tid >> 6;  // 0..3
#pragma unroll
    for (int i = 0; i < 16; ++i) {
        int cl = cl0 + i * 4;
        tile[cl][sl] = (bf16)x[((size_t)n * EMBED + (c0 + cl)) * SEQ + s0 + sl];
    }
    __syncthreads();
    int cl  = tid & 63;
    int sl0 = tid >> 6;
#pragma unroll
    for (int i = 0; i < 16; ++i) {
        int s = sl0 + i * 4;
        tok[((size_t)n * SEQ + (s0 + s)) * EMBED + c0 + cl] = tile[cl][s];
    }
}

// ---------------------------------------------------------------------------
// K1: qkv. 1-D grid, xcd-swizzled: blocks sharing (n,bm) (same A-tile) get
//   the same blockIdx%8 -> same XCD L2 (reuse heuristic, speed-only).
// ---------------------------------------------------------------------------
__global__ __launch_bounds__(256) void k_qkv(const bf16* __restrict__ tok,
                                             const bf16* __restrict__ wqkv,
                                             bf16* __restrict__ qout,
                                             bf16* __restrict__ kout,
                                             bf16* __restrict__ vtout) {
    int b    = blockIdx.x;       // 1152 blocks
    int bm   = b & 7;            // 8 s-tiles -> XCD
    int g    = b >> 3;
    int bn   = g % 9;            // 9 o-tiles
    int n    = g / 9;
    int wave = threadIdx.x >> 6;
    int lane = threadIdx.x & 63;
    int row16 = lane & 15;
    int quad  = lane >> 4;
    int s_base = bm * 128 + (wave >> 1) * 64;
    int o_base = bn * 128 + (wave & 1) * 64;

    const bf16* A = tok + (size_t)n * SEQ * EMBED;

    f32x4 acc[4][4] = {};
    for (int kk = 0; kk < EMBED; kk += 32) {
        bf16x8 af[4], bfr[4];
#pragma unroll
        for (int mt = 0; mt < 4; ++mt)
            af[mt] = *reinterpret_cast<const bf16x8*>(
                A + (size_t)(s_base + mt * 16 + row16) * EMBED + kk + quad * 8);
#pragma unroll
        for (int nt = 0; nt < 4; ++nt)
            bfr[nt] = *reinterpret_cast<const bf16x8*>(
                wqkv + (size_t)(o_base + nt * 16 + row16) * EMBED + kk + quad * 8);
#pragma unroll
        for (int mt = 0; mt < 4; ++mt)
#pragma unroll
            for (int nt = 0; nt < 4; ++nt)
                acc[mt][nt] = MFMA16(af[mt], bfr[nt], acc[mt][nt]);
    }

    int part = (bn * 128) / EMBED;  // o-tile never crosses a part boundary
#pragma unroll
    for (int mt = 0; mt < 4; ++mt)
#pragma unroll
        for (int nt = 0; nt < 4; ++nt) {
            int o   = o_base + nt * 16 + row16;
            int rem = o - part * EMBED;
            int h = rem >> 6;
            int d = rem & 63;
            if (part < 2) {
                bf16* dst = (part == 0) ? qout : kout;
#pragma unroll
                for (int r = 0; r < 4; ++r) {
                    int s = s_base + mt * 16 + quad * 4 + r;
                    dst[(((size_t)n * NH + h) * SEQ + s) * HD + d] = (bf16)acc[mt][nt][r];
                }
            } else {
                int s = s_base + mt * 16 + quad * 4;  // 4 consecutive s -> 8B store
                bf16x4 pack;
#pragma unroll
                for (int r = 0; r < 4; ++r) pack[r] = (bf16)acc[mt][nt][r];
                *reinterpret_cast<bf16x4*>(
                    &vtout[(((size_t)n * NH + h) * HD + d) * SEQ + s]) = pack;
            }
        }
}

// ---------------------------------------------------------------------------
// K2: attention v3.
//   - 1-D grid swizzled so all 16 q-tile blocks of one head share an XCD:
//     per-XCD K/V working set = 12 heads * 262KB = 3.1MB < 4MB L2 -> K/V
//     miss to LLC once per head instead of ~8x.
//   - K/V tiles staged to LDS via global_load_lds (dbl-buffered, 1 barrier
//     per iter; prefetch issued right after barrier, drained at next barrier
//     after a full compute section).
//   - S^T = K*Q^T trick (R5) for packed P round-trip; unnormalized exp,
//     one reduction at the end.
// ---------------------------------------------------------------------------
__global__ __launch_bounds__(256) void k_attn(const bf16* __restrict__ q,
                                              const bf16* __restrict__ kmat,
                                              const bf16* __restrict__ vT,
                                              bf16* __restrict__ ao) {
    __shared__ __align__(16) bf16 ktile[2][64 * HD];   // [t][d], 8KB each
    __shared__ __align__(16) bf16 vtile[2][64 * 64];   // [d][t], 8KB each
    __shared__ __align__(16) bf16 pshare[4][16][72];   // wave-private P tile

    int b     = blockIdx.x;      // 1536 blocks
    int lane8 = b & 7;           // -> XCD (round-robin heuristic)
    int g     = b >> 3;
    int nh    = (g % 12) * 8 + lane8;   // all qt of one nh share lane8
    int qt    = g / 12;
    int n = nh / NH, h = nh % NH;

    int wave = threadIdx.x >> 6;
    int lane = threadIdx.x & 63;
    int row16 = lane & 15;
    int quad  = lane >> 4;
    int s_row = qt * 64 + wave * 16;

    const bf16* qh = q    + ((size_t)n * NH + h) * SEQ * HD;
    const bf16* kh = kmat + ((size_t)n * NH + h) * SEQ * HD;
    const bf16* vh = vT   + ((size_t)n * NH + h) * HD * SEQ;

    bf16x8 qf0 = *reinterpret_cast<const bf16x8*>(qh + (size_t)(s_row + row16) * HD + quad * 8);
    bf16x8 qf1 = *reinterpret_cast<const bf16x8*>(qh + (size_t)(s_row + row16) * HD + 32 + quad * 8);

    // each wave stages 16 K-rows and 16 V-rows of the 64-wide tile
    int r0 = wave * 16;
    int vrow = lane >> 3;        // 0..7 within an 8-row staging instr
    int vcol = (lane & 7) * 8;   // 8 elems = 16B per lane
    auto stage = [&](int t0, int bi) {
#pragma unroll
        for (int j = 0; j < 16; j += 8) {
            // K rows contiguous in global: lane*8 walks 8 rows exactly
            gload_lds16(kh + (size_t)(t0 + r0 + j) * HD + lane * 8,
                        &ktile[bi][(r0 + j) * HD]);
            // V rows are SEQ apart: per-lane row/col split
            gload_lds16(vh + (size_t)(r0 + j + vrow) * SEQ + t0 + vcol,
                        &vtile[bi][(r0 + j) * 64]);
        }
    };

    stage(0, 0);

    float lsum[4] = {0.f, 0.f, 0.f, 0.f};
    f32x4 oacc[4] = {};
    const float kScale = 0.180336879f;  // log2(e)/8

    for (int it = 0; it < 16; ++it) {
        __syncthreads();                 // drains own staging loads + publishes LDS
        int cur = it & 1;
        if (it + 1 < 16) stage((it + 1) * 64, cur ^ 1);  // prefetch next tile

        const bf16* kb = &ktile[cur][0];
        const bf16* vb = &vtile[cur][0];

        // S^T = K*Q^T: lane holds S[m=row16][t=nt*16+quad*4+r]
        f32x4 sacc[4] = {};
#pragma unroll
        for (int nt = 0; nt < 4; ++nt) {
            bf16x8 kf0 = *reinterpret_cast<const bf16x8*>(kb + (nt * 16 + row16) * HD + quad * 8);
            bf16x8 kf1 = *reinterpret_cast<const bf16x8*>(kb + (nt * 16 + row16) * HD + 32 + quad * 8);
            sacc[nt] = MFMA16(kf0, qf0, sacc[nt]);
            sacc[nt] = MFMA16(kf1, qf1, sacc[nt]);
        }
        // P = exp(S/8) unnormalized; packed 8B LDS writes
#pragma unroll
        for (int nt = 0; nt < 4; ++nt) {
            bf16x4 pk;
            float ps = 0.f;
#pragma unroll
            for (int r = 0; r < 4; ++r) {
                float e = __builtin_amdgcn_exp2f(sacc[nt][r] * kScale);
                ps += e;
                pk[r] = (bf16)e;
            }
            lsum[nt] += ps;
            *reinterpret_cast<bf16x4*>(&pshare[wave][row16][nt * 16 + quad * 4]) = pk;
        }
        __builtin_amdgcn_wave_barrier();  // wave-private LDS write -> read order
        bf16x8 pf0 = *reinterpret_cast<const bf16x8*>(&pshare[wave][row16][quad * 8]);
        bf16x8 pf1 = *reinterpret_cast<const bf16x8*>(&pshare[wave][row16][32 + quad * 8]);
        __builtin_amdgcn_wave_barrier();  // read -> next iter's writes
        // O += P*V
#pragma unroll
        for (int dt = 0; dt < 4; ++dt) {
            bf16x8 vf0 = *reinterpret_cast<const bf16x8*>(vb + (dt * 16 + row16) * 64 + quad * 8);
            bf16x8 vf1 = *reinterpret_cast<const bf16x8*>(vb + (dt * 16 + row16) * 64 + 32 + quad * 8);
            oacc[dt] = MFMA16(pf0, vf0, oacc[dt]);
            oacc[dt] = MFMA16(pf1, vf1, oacc[dt]);
        }
    }

    // row-sum: lane's lsum covers t ≡ {4*quad..4*quad+3} mod 16 for row=row16
    float tot = (lsum[0] + lsum[1]) + (lsum[2] + lsum[3]);
    tot += __shfl_xor(tot, 16, 64);
    tot += __shfl_xor(tot, 32, 64);
    float inv = 1.0f / tot;  // valid for row = lane&15

    float linv[4];
#pragma unroll
    for (int r = 0; r < 4; ++r) linv[r] = __shfl(inv, quad * 4 + r, 64);

#pragma unroll
    for (int dt = 0; dt < 4; ++dt)
#pragma unroll
        for (int r = 0; r < 4; ++r) {
            int s = s_row + quad * 4 + r;
            int d = dt * 16 + row16;
            ao[((size_t)n * SEQ + s) * EMBED + h * HD + d] = (bf16)(oacc[dt][r] * linv[r]);
        }
}

// ---------------------------------------------------------------------------
// K3: out[n][o][s] = bias[o] + sum_c ao[n][s][c] * wout[o][c]   (f32 output)
// ---------------------------------------------------------------------------
__global__ __launch_bounds__(256) void k_proj(const bf16* __restrict__ ao,
                                              const bf16* __restrict__ wout,
                                              const float* __restrict__ bout,
                                              float* __restrict__ out) {
    int b    = blockIdx.x;       // 384 blocks
    int bm   = b & 7;            // 8 s-tiles -> XCD
    int g    = b >> 3;
    int bn   = g % 3;            // 3 o-tiles
    int n    = g / 3;
    int wave = threadIdx.x >> 6;
    int lane = threadIdx.x & 63;
    int row16 = lane & 15;
    int quad  = lane >> 4;
    int s_base = bm * 128 + (wave >> 1) * 64;
    int o_base = bn * 128 + (wave & 1) * 64;

    const bf16* A = ao + (size_t)n * SEQ * EMBED;

    f32x4 acc[4][4] = {};
    for (int kk = 0; kk < EMBED; kk += 32) {
        bf16x8 af[4], bfr[4];
#pragma unroll
        for (int mt = 0; mt < 4; ++mt)
            af[mt] = *reinterpret_cast<const bf16x8*>(
                A + (size_t)(s_base + mt * 16 + row16) * EMBED + kk + quad * 8);
#pragma unroll
        for (int nt = 0; nt < 4; ++nt)
            bfr[nt] = *reinterpret_cast<const bf16x8*>(
                wout + (size_t)(o_base + nt * 16 + row16) * EMBED + kk + quad * 8);
#pragma unroll
        for (int mt = 0; mt < 4; ++mt)
#pragma unroll
            for (int nt = 0; nt < 4; ++nt)
                acc[mt][nt] = MFMA16(af[mt], bfr[nt], acc[mt][nt]);
    }

#pragma unroll
    for (int nt = 0; nt < 4; ++nt) {
        int o = o_base + nt * 16 + row16;
        float bias = bout[o];
#pragma unroll
        for (int mt = 0; mt < 4; ++mt) {
            int s = s_base + mt * 16 + quad * 4;  // 4 consecutive s, 16B store
            f32x4 pack;
#pragma unroll
            for (int r = 0; r < 4; ++r) pack[r] = acc[mt][nt][r] + bias;
            *reinterpret_cast<f32x4*>(out + ((size_t)n * EMBED + o) * SEQ + s) = pack;
        }
    }
}

// ---------------------------------------------------------------------------
extern "C" void kernel_launch(void* const* d_in, const int* in_sizes, int n_in,
                              void* d_out, int out_size, void* d_ws, size_t ws_size,
                              hipStream_t stream) {
    const float *x = nullptr, *wqkv = nullptr, *wout = nullptr, *bout = nullptr;
    for (int i = 0; i < n_in; ++i) {
        switch (in_sizes[i]) {
            case NBATCH * EMBED * SEQ:   x    = (const float*)d_in[i]; break;  // 6291456
            case 3 * EMBED * EMBED:      wqkv = (const float*)d_in[i]; break;  // 442368
            case EMBED * EMBED:          wout = (const float*)d_in[i]; break;  // 147456
            case EMBED:                  bout = (const float*)d_in[i]; break;  // 384
        }
    }
    float* out = (float*)d_out;

    bf16* ws = (bf16*)d_ws;
    const size_t NE = (size_t)NBATCH * SEQ * EMBED;  // 6.29M elems
    bf16* tok   = ws;
    bf16* q     = ws + NE;
    bf16* k     = ws + 2 * NE;
    bf16* vT    = ws + 3 * NE;
    bf16* ao    = ws + 4 * NE;
    bf16* wqkvb = ws + 5 * NE;
    bf16* woutb = wqkvb + 3 * EMBED * EMBED;

    const int nqkv = 3 * EMBED * EMBED;
    const int nout = EMBED * EMBED;
    k_cvt<<<dim3((nqkv + 255) / 256), 256, 0, stream>>>(wqkv, wqkvb, nqkv);
    k_cvt<<<dim3((nout + 255) / 256), 256, 0, stream>>>(wout, woutb, nout);

    k_transpose<<<dim3(16, 6, 16), 256, 0, stream>>>(x, tok);
    k_qkv<<<dim3(1152), 256, 0, stream>>>(tok, wqkvb, q, k, vT);
    k_attn<<<dim3(1536), 256, 0, stream>>>(q, k, vT, ao);
    k_proj<<<dim3(384), 256, 0, stream>>>(ao, woutb, bout, out);
}

// Round 7
// 189.087 us; speedup vs baseline: 1.8576x; 1.2690x over previous
//
#include <hip/hip_runtime.h>
#include <hip/hip_bf16.h>

#define EMBED 384
#define SEQ   1024
#define NBATCH 16
#define NH    6
#define HD    64

typedef __bf16 bf16;
typedef bf16  bf16x8 __attribute__((ext_vector_type(8)));
typedef bf16  bf16x4 __attribute__((ext_vector_type(4)));
typedef float f32x4  __attribute__((ext_vector_type(4)));

#define MFMA16(a, b, c) __builtin_amdgcn_mfma_f32_16x16x32_bf16((a), (b), (c), 0, 0, 0)

// async global->LDS, 16B per lane; LDS dst = wave-uniform base + lane*16
__device__ __forceinline__ void gload_lds16(const void* g, void* l) {
    __builtin_amdgcn_global_load_lds(
        (const __attribute__((address_space(1))) void*)g,
        (__attribute__((address_space(3))) void*)l, 16, 0, 0);
}

// ---------------------------------------------------------------------------
// K-1: f32 -> bf16 weight conversion (w_qkv, w_out)
// ---------------------------------------------------------------------------
__global__ __launch_bounds__(256) void k_cvt(const float* __restrict__ src,
                                             bf16* __restrict__ dst, int n) {
    int i = blockIdx.x * 256 + threadIdx.x;
    if (i < n) dst[i] = (bf16)src[i];
}

// ---------------------------------------------------------------------------
// K0: x[n][c][s] (f32) -> tok[n][s][c] (bf16)  tile transpose through LDS
// ---------------------------------------------------------------------------
__global__ __launch_bounds__(256) void k_transpose(const float* __restrict__ x,
                                                   bf16* __restrict__ tok) {
    __shared__ bf16 tile[64][66];
    int n  = blockIdx.z;
    int s0 = blockIdx.x * 64;
    int c0 = blockIdx.y * 64;
    int tid = threadIdx.x;

    int sl  = tid & 63;
    int cl0 = tid >> 6;  // 0..3
#pragma unroll
    for (int i = 0; i < 16; ++i) {
        int cl = cl0 + i * 4;
        tile[cl][sl] = (bf16)x[((size_t)n * EMBED + (c0 + cl)) * SEQ + s0 + sl];
    }
    __syncthreads();
    int cl  = tid & 63;
    int sl0 = tid >> 6;
#pragma unroll
    for (int i = 0; i < 16; ++i) {
        int s = sl0 + i * 4;
        tok[((size_t)n * SEQ + (s0 + s)) * EMBED + c0 + cl] = tile[cl][s];
    }
}

// ---------------------------------------------------------------------------
// K1: qkv, m97-style: double-buffered LDS staging (BK=32) via global_load_lds.
//   128(s) x 128(o) block tile, 4 waves of 64x64. XCD swizzle: blocks sharing
//   an A-tile share blockIdx%8.
// ---------------------------------------------------------------------------
__global__ __launch_bounds__(256) void k_qkv(const bf16* __restrict__ tok,
                                             const bf16* __restrict__ wqkv,
                                             bf16* __restrict__ qout,
                                             bf16* __restrict__ kout,
                                             bf16* __restrict__ vtout) {
    __shared__ __align__(16) bf16 At[2][128 * 32];  // 8KB each, 64B rows
    __shared__ __align__(16) bf16 Bt[2][128 * 32];

    int b    = blockIdx.x;       // 1152 blocks
    int bm   = b & 7;            // 8 s-tiles -> XCD
    int g    = b >> 3;
    int bn   = g % 9;            // 9 o-tiles
    int n    = g / 9;
    int wave = threadIdx.x >> 6;
    int lane = threadIdx.x & 63;
    int row16 = lane & 15;
    int quad  = lane >> 4;
    int sw_base = (wave >> 1) * 64;   // wave row offset within tile
    int ow_base = (wave & 1) * 64;

    const bf16* Ag = tok  + ((size_t)n * SEQ + bm * 128) * EMBED;
    const bf16* Bg = wqkv + (size_t)bn * 128 * EMBED;

    // staging: wave w covers tile rows 32w..32w+31 (two 16-row slabs of 1KB)
    int srow = lane >> 2;        // 0..15 within slab
    int scol = (lane & 3) * 8;   // 8 elems = 16B
    auto stage = [&](int kk, int bi) {
#pragma unroll
        for (int j = 0; j < 32; j += 16) {
            int R = wave * 32 + j;
            gload_lds16(Ag + (size_t)(R + srow) * EMBED + kk + scol, &At[bi][R * 32]);
            gload_lds16(Bg + (size_t)(R + srow) * EMBED + kk + scol, &Bt[bi][R * 32]);
        }
    };

    stage(0, 0);

    f32x4 acc[4][4] = {};
    for (int step = 0; step < 12; ++step) {
        __syncthreads();                       // drain staging, publish LDS
        int cur = step & 1;
        if (step + 1 < 12) stage((step + 1) * 32, cur ^ 1);

        bf16x8 af[4], bfr[4];
#pragma unroll
        for (int mt = 0; mt < 4; ++mt)
            af[mt] = *reinterpret_cast<const bf16x8*>(
                &At[cur][(sw_base + mt * 16 + row16) * 32 + quad * 8]);
#pragma unroll
        for (int nt = 0; nt < 4; ++nt)
            bfr[nt] = *reinterpret_cast<const bf16x8*>(
                &Bt[cur][(ow_base + nt * 16 + row16) * 32 + quad * 8]);
#pragma unroll
        for (int mt = 0; mt < 4; ++mt)
#pragma unroll
            for (int nt = 0; nt < 4; ++nt)
                acc[mt][nt] = MFMA16(af[mt], bfr[nt], acc[mt][nt]);
    }

    int s_base = bm * 128 + sw_base;
    int o_base = bn * 128 + ow_base;
    int part = (bn * 128) / EMBED;  // o-tile never crosses a part boundary
#pragma unroll
    for (int mt = 0; mt < 4; ++mt)
#pragma unroll
        for (int nt = 0; nt < 4; ++nt) {
            int o   = o_base + nt * 16 + row16;
            int rem = o - part * EMBED;
            int h = rem >> 6;
            int d = rem & 63;
            if (part < 2) {
                bf16* dst = (part == 0) ? qout : kout;
#pragma unroll
                for (int r = 0; r < 4; ++r) {
                    int s = s_base + mt * 16 + quad * 4 + r;
                    dst[(((size_t)n * NH + h) * SEQ + s) * HD + d] = (bf16)acc[mt][nt][r];
                }
            } else {
                int s = s_base + mt * 16 + quad * 4;  // 4 consecutive s -> 8B store
                bf16x4 pack;
#pragma unroll
                for (int r = 0; r < 4; ++r) pack[r] = (bf16)acc[mt][nt][r];
                *reinterpret_cast<bf16x4*>(
                    &vtout[(((size_t)n * NH + h) * HD + d) * SEQ + s]) = pack;
            }
        }
}

// ---------------------------------------------------------------------------
// K2: attention v4 = v3 + XOR-swizzled K/V LDS layout.
//   Element (row, chunk c) [16B chunks, 8 per 64-elem row] stored at
//   row*128B + (c ^ (row&7))*16B  -> b128 fragment reads hit 8 distinct
//   chunk positions (conflict floor) instead of 4. Staging stays
//   global_load_lds: lane-linear LDS writes, swizzle folded into the
//   per-lane GLOBAL source chunk.
// ---------------------------------------------------------------------------
__global__ __launch_bounds__(256) void k_attn(const bf16* __restrict__ q,
                                              const bf16* __restrict__ kmat,
                                              const bf16* __restrict__ vT,
                                              bf16* __restrict__ ao) {
    __shared__ __align__(16) bf16 ktile[2][64 * 64];   // swizzled [t][d]
    __shared__ __align__(16) bf16 vtile[2][64 * 64];   // swizzled [d][t]
    __shared__ __align__(16) bf16 pshare[4][16][72];   // wave-private P tile

    int b     = blockIdx.x;      // 1536 blocks
    int lane8 = b & 7;           // -> XCD (round-robin heuristic)
    int g     = b >> 3;
    int nh    = (g % 12) * 8 + lane8;   // all qt of one nh share lane8
    int qt    = g / 12;
    int n = nh / NH, h = nh % NH;

    int wave = threadIdx.x >> 6;
    int lane = threadIdx.x & 63;
    int row16 = lane & 15;
    int quad  = lane >> 4;
    int sw    = row16 & 7;       // read-side swizzle key
    int s_row = qt * 64 + wave * 16;

    const bf16* qh = q    + ((size_t)n * NH + h) * SEQ * HD;
    const bf16* kh = kmat + ((size_t)n * NH + h) * SEQ * HD;
    const bf16* vh = vT   + ((size_t)n * NH + h) * HD * SEQ;

    bf16x8 qf0 = *reinterpret_cast<const bf16x8*>(qh + (size_t)(s_row + row16) * HD + quad * 8);
    bf16x8 qf1 = *reinterpret_cast<const bf16x8*>(qh + (size_t)(s_row + row16) * HD + 32 + quad * 8);

    // wave w stages tile rows 16w..16w+15 (two 8-row 1KB slabs)
    int r0 = wave * 16;
    auto stage = [&](int t0, int bi) {
#pragma unroll
        for (int j = 0; j < 16; j += 8) {
            int R   = r0 + j;
            int row = R + (lane >> 3);             // tile row this lane feeds
            int ck  = (lane & 7) ^ (row & 7);      // swizzled source chunk
            gload_lds16(kh + (size_t)(t0 + row) * HD + ck * 8,
                        &ktile[bi][R * 64]);
            gload_lds16(vh + (size_t)row * SEQ + t0 + ck * 8,
                        &vtile[bi][R * 64]);
        }
    };

    stage(0, 0);

    float lsum[4] = {0.f, 0.f, 0.f, 0.f};
    f32x4 oacc[4] = {};
    const float kScale = 0.180336879f;  // log2(e)/8

    for (int it = 0; it < 16; ++it) {
        __syncthreads();                 // drains own staging loads + publishes LDS
        int cur = it & 1;
        if (it + 1 < 16) stage((it + 1) * 64, cur ^ 1);  // prefetch next tile

        const bf16* kb = &ktile[cur][0];
        const bf16* vb = &vtile[cur][0];

        // S^T = K*Q^T: lane holds S[m=row16][t=nt*16+quad*4+r]
        f32x4 sacc[4] = {};
#pragma unroll
        for (int nt = 0; nt < 4; ++nt) {
            bf16x8 kf0 = *reinterpret_cast<const bf16x8*>(
                kb + (nt * 16 + row16) * 64 + ((quad ^ sw) * 8));
            bf16x8 kf1 = *reinterpret_cast<const bf16x8*>(
                kb + (nt * 16 + row16) * 64 + (((4 + quad) ^ sw) * 8));
            sacc[nt] = MFMA16(kf0, qf0, sacc[nt]);
            sacc[nt] = MFMA16(kf1, qf1, sacc[nt]);
        }
        // P = exp(S/8) unnormalized; packed 8B LDS writes
#pragma unroll
        for (int nt = 0; nt < 4; ++nt) {
            bf16x4 pk;
            float ps = 0.f;
#pragma unroll
            for (int r = 0; r < 4; ++r) {
                float e = __builtin_amdgcn_exp2f(sacc[nt][r] * kScale);
                ps += e;
                pk[r] = (bf16)e;
            }
            lsum[nt] += ps;
            *reinterpret_cast<bf16x4*>(&pshare[wave][row16][nt * 16 + quad * 4]) = pk;
        }
        __builtin_amdgcn_wave_barrier();  // wave-private LDS write -> read order
        bf16x8 pf0 = *reinterpret_cast<const bf16x8*>(&pshare[wave][row16][quad * 8]);
        bf16x8 pf1 = *reinterpret_cast<const bf16x8*>(&pshare[wave][row16][32 + quad * 8]);
        __builtin_amdgcn_wave_barrier();  // read -> next iter's writes
        // O += P*V
#pragma unroll
        for (int dt = 0; dt < 4; ++dt) {
            bf16x8 vf0 = *reinterpret_cast<const bf16x8*>(
                vb + (dt * 16 + row16) * 64 + ((quad ^ sw) * 8));
            bf16x8 vf1 = *reinterpret_cast<const bf16x8*>(
                vb + (dt * 16 + row16) * 64 + (((4 + quad) ^ sw) * 8));
            oacc[dt] = MFMA16(pf0, vf0, oacc[dt]);
            oacc[dt] = MFMA16(pf1, vf1, oacc[dt]);
        }
    }

    // row-sum: lane's lsum covers t ≡ {4*quad..4*quad+3} mod 16 for row=row16
    float tot = (lsum[0] + lsum[1]) + (lsum[2] + lsum[3]);
    tot += __shfl_xor(tot, 16, 64);
    tot += __shfl_xor(tot, 32, 64);
    float inv = 1.0f / tot;  // valid for row = lane&15

    float linv[4];
#pragma unroll
    for (int r = 0; r < 4; ++r) linv[r] = __shfl(inv, quad * 4 + r, 64);

#pragma unroll
    for (int dt = 0; dt < 4; ++dt)
#pragma unroll
        for (int r = 0; r < 4; ++r) {
            int s = s_row + quad * 4 + r;
            int d = dt * 16 + row16;
            ao[((size_t)n * SEQ + s) * EMBED + h * HD + d] = (bf16)(oacc[dt][r] * linv[r]);
        }
}

// ---------------------------------------------------------------------------
// K3: out[n][o][s] = bias[o] + sum_c ao[n][s][c] * wout[o][c]   (f32 output)
//   64(s) x 128(o) block tile -> 768 blocks (3/CU), wave tile 32x64.
// ---------------------------------------------------------------------------
__global__ __launch_bounds__(256) void k_proj(const bf16* __restrict__ ao,
                                              const bf16* __restrict__ wout,
                                              const float* __restrict__ bout,
                                              float* __restrict__ out) {
    int b    = blockIdx.x;       // 768 blocks
    int bm   = b & 15;           // 16 s-tiles of 64; same (n,bm) share b%8
    int g    = b >> 4;
    int bn   = g % 3;            // 3 o-tiles
    int n    = g / 3;
    int wave = threadIdx.x >> 6;
    int lane = threadIdx.x & 63;
    int row16 = lane & 15;
    int quad  = lane >> 4;
    int s_base = bm * 64 + (wave >> 1) * 32;
    int o_base = bn * 128 + (wave & 1) * 64;

    const bf16* A = ao + (size_t)n * SEQ * EMBED;

    f32x4 acc[2][4] = {};
    for (int kk = 0; kk < EMBED; kk += 32) {
        bf16x8 af[2], bfr[4];
#pragma unroll
        for (int mt = 0; mt < 2; ++mt)
            af[mt] = *reinterpret_cast<const bf16x8*>(
                A + (size_t)(s_base + mt * 16 + row16) * EMBED + kk + quad * 8);
#pragma unroll
        for (int nt = 0; nt < 4; ++nt)
            bfr[nt] = *reinterpret_cast<const bf16x8*>(
                wout + (size_t)(o_base + nt * 16 + row16) * EMBED + kk + quad * 8);
#pragma unroll
        for (int mt = 0; mt < 2; ++mt)
#pragma unroll
            for (int nt = 0; nt < 4; ++nt)
                acc[mt][nt] = MFMA16(af[mt], bfr[nt], acc[mt][nt]);
    }

#pragma unroll
    for (int nt = 0; nt < 4; ++nt) {
        int o = o_base + nt * 16 + row16;
        float bias = bout[o];
#pragma unroll
        for (int mt = 0; mt < 2; ++mt) {
            int s = s_base + mt * 16 + quad * 4;  // 4 consecutive s, 16B store
            f32x4 pack;
#pragma unroll
            for (int r = 0; r < 4; ++r) pack[r] = acc[mt][nt][r] + bias;
            *reinterpret_cast<f32x4*>(out + ((size_t)n * EMBED + o) * SEQ + s) = pack;
        }
    }
}

// ---------------------------------------------------------------------------
extern "C" void kernel_launch(void* const* d_in, const int* in_sizes, int n_in,
                              void* d_out, int out_size, void* d_ws, size_t ws_size,
                              hipStream_t stream) {
    const float *x = nullptr, *wqkv = nullptr, *wout = nullptr, *bout = nullptr;
    for (int i = 0; i < n_in; ++i) {
        switch (in_sizes[i]) {
            case NBATCH * EMBED * SEQ:   x    = (const float*)d_in[i]; break;  // 6291456
            case 3 * EMBED * EMBED:      wqkv = (const float*)d_in[i]; break;  // 442368
            case EMBED * EMBED:          wout = (const float*)d_in[i]; break;  // 147456
            case EMBED:                  bout = (const float*)d_in[i]; break;  // 384
        }
    }
    float* out = (float*)d_out;

    bf16* ws = (bf16*)d_ws;
    const size_t NE = (size_t)NBATCH * SEQ * EMBED;  // 6.29M elems
    bf16* tok   = ws;
    bf16* q     = ws + NE;
    bf16* k     = ws + 2 * NE;
    bf16* vT    = ws + 3 * NE;
    bf16* ao    = ws + 4 * NE;
    bf16* wqkvb = ws + 5 * NE;
    bf16* woutb = wqkvb + 3 * EMBED * EMBED;

    const int nqkv = 3 * EMBED * EMBED;
    const int nout = EMBED * EMBED;
    k_cvt<<<dim3((nqkv + 255) / 256), 256, 0, stream>>>(wqkv, wqkvb, nqkv);
    k_cvt<<<dim3((nout + 255) / 256), 256, 0, stream>>>(wout, woutb, nout);

    k_transpose<<<dim3(16, 6, 16), 256, 0, stream>>>(x, tok);
    k_qkv<<<dim3(1152), 256, 0, stream>>>(tok, wqkvb, q, k, vT);
    k_attn<<<dim3(1536), 256, 0, stream>>>(q, k, vT, ao);
    k_proj<<<dim3(768), 256, 0, stream>>>(ao, woutb, bout, out);
}